// Round 12
// baseline (1230.360 us; speedup 1.0000x reference)
//
#include <hip/hip_runtime.h>
#include <math.h>

// Problem constants
#define Bn    32
#define Tn    2000
#define Mrows (Bn * Tn)        // 64000
#define ENC2n 1024
#define ATTNn 512
#define DECn  512
#define NKn   10
#define KWn   100
#define PADn  50

// workspace layout (floats):
//   [0, 640000)            tmpconv [64000][10]
//   [OFF_DB, +16384)       DB[32][512] = b_enc + dec_e
//   [OFF_SCORE, +64000)    score [64000]
//   [OFF_WT, +262144)      Wt f16 [512 col][1024 k]
//   [OFF_AF16, ...)        Af16 [64000][1024] f16
#define OFF_DB    (Mrows * NKn)
#define OFF_SCORE (OFF_DB + Bn * ATTNn)
#define OFF_WT    (OFF_SCORE + Mrows)
#define OFF_AF16  (OFF_WT + 262144)

typedef _Float16 v8h __attribute__((ext_vector_type(8)));
typedef float f32x4 __attribute__((ext_vector_type(4)));

__device__ __forceinline__ float fast_tanh(float v) {
  const float e = __expf(2.f * v);
  return 1.f - 2.f * __builtin_amdgcn_rcpf(e + 1.f);
}

__device__ __forceinline__ void gload_lds16(const void* g, void* l) {
  __builtin_amdgcn_global_load_lds(
      (const __attribute__((address_space(1))) void*)g,
      (__attribute__((address_space(3))) void*)l, 16, 0, 0);
}

// ---------------------------------------------------------------------------
__global__ __launch_bounds__(256) void k_wt(const float* __restrict__ W,
                                            _Float16* __restrict__ Wt) {
  __shared__ float sh[32][33];
  const int x = threadIdx.x & 31, y = threadIdx.x >> 5;
  const int k0 = blockIdx.x * 32, c0 = blockIdx.y * 32;
  for (int i = y; i < 32; i += 8) sh[i][x] = W[(size_t)(k0 + i) * ATTNn + c0 + x];
  __syncthreads();
  for (int i = y; i < 32; i += 8)
    Wt[(size_t)(c0 + i) * ENC2n + k0 + x] = (_Float16)sh[x][i];
}

__global__ __launch_bounds__(256) void k_acvt(const float* __restrict__ A,
                                              _Float16* __restrict__ Af) {
  const size_t total = (size_t)Mrows * ENC2n;
  const size_t stride = (size_t)gridDim.x * 256 * 8;
  for (size_t i = ((size_t)blockIdx.x * 256 + threadIdx.x) * 8; i < total;
       i += stride) {
    const float4 a = *(const float4*)(A + i);
    const float4 b = *(const float4*)(A + i + 4);
    v8h h;
    h[0] = (_Float16)a.x; h[1] = (_Float16)a.y;
    h[2] = (_Float16)a.z; h[3] = (_Float16)a.w;
    h[4] = (_Float16)b.x; h[5] = (_Float16)b.y;
    h[6] = (_Float16)b.z; h[7] = (_Float16)b.w;
    *(v8h*)(Af + i) = h;
  }
}

__global__ __launch_bounds__(256) void k_conv(const float* __restrict__ alpha,
                                              const float* __restrict__ Wconv,
                                              float* __restrict__ ws) {
  __shared__ float sh[256 + KWn - 1];
  __shared__ float wc[NKn * KWn];
  const int b = blockIdx.y;
  const int t0 = blockIdx.x * 256;
  const int tid = threadIdx.x;

  for (int i = tid; i < NKn * KWn; i += 256) wc[i] = Wconv[i];
  const float* __restrict__ arow = alpha + b * Tn;
  for (int i = tid; i < 256 + KWn - 1; i += 256) {
    const int t = t0 - PADn + i;
    sh[i] = (t >= 0 && t < Tn) ? arow[t] : 0.f;
  }
  __syncthreads();

  const int t = t0 + tid;
  if (t < Tn) {
    float acc[NKn];
#pragma unroll
    for (int k = 0; k < NKn; ++k) acc[k] = 0.f;
    for (int i = 0; i < KWn; ++i) {
      const float a = sh[tid + i];
#pragma unroll
      for (int k = 0; k < NKn; ++k) acc[k] = fmaf(a, wc[k * KWn + i], acc[k]);
    }
    float* tp = ws + (size_t)(b * Tn + t) * NKn;
#pragma unroll
    for (int k = 0; k < NKn; ++k) tp[k] = acc[k];
    ws[OFF_SCORE + b * Tn + t] = 0.f;
  }
}

__global__ __launch_bounds__(512) void k_dec(const float* __restrict__ h,
                                             const float* __restrict__ Wdec,
                                             const float* __restrict__ benc,
                                             float* __restrict__ ws) {
  __shared__ float sh[DECn];
  const int b = blockIdx.x;
  const int a = threadIdx.x;
  sh[a] = h[b * DECn + a];
  __syncthreads();
  float acc = 0.f;
  for (int d = 0; d < DECn; ++d) acc = fmaf(sh[d], Wdec[d * ATTNn + a], acc);
  ws[OFF_DB + b * ATTNn + a] = benc[a] + acc;
}

#define BM 128
#define BN 128
#define BK 32
#define NT (ENC2n / BK)   // 32

// ---------------------------------------------------------------------------
// k_main<MODE>: R9 DMA kernel.
//   MODE 0: real (full epilogue -> score).     [reference, correct output]
//   MODE 1: 4x K-loop, WITH barriers/waits.    [ablation A]
//   MODE 2: 4x K-loop, NO barriers/waits.      [ablation B - racy, discarded]
// ---------------------------------------------------------------------------
#define DMAT(buf, kt) {                                                      \
  gload_lds16(aA0 + (kt) * BK, &Ab[buf][(2 * wv) * 512]);                    \
  gload_lds16(aA1 + (kt) * BK, &Ab[buf][(2 * wv + 1) * 512]);                \
  gload_lds16(aW0 + (kt) * BK, &Wb[buf][(2 * wv) * 512]);                    \
  gload_lds16(aW1 + (kt) * BK, &Wb[buf][(2 * wv + 1) * 512]); }

#define COMPUTE(buf) {                                                       \
  v8h af[4], bf[4];                                                          \
  _Pragma("unroll")                                                          \
  for (int m = 0; m < 4; ++m)                                                \
    af[m] = *(const v8h*)&Ab[buf][(wm * 4 + m) * 512 + lane * 8];            \
  _Pragma("unroll")                                                          \
  for (int n = 0; n < 4; ++n)                                                \
    bf[n] = *(const v8h*)&Wb[buf][(wn * 4 + n) * 512 + lane * 8];            \
  __builtin_amdgcn_s_setprio(1);                                             \
  _Pragma("unroll")                                                          \
  for (int m = 0; m < 4; ++m)                                                \
    _Pragma("unroll")                                                        \
    for (int n = 0; n < 4; ++n)                                              \
      acc[m][n] = __builtin_amdgcn_mfma_f32_16x16x32_f16(af[m], bf[n],       \
                                                         acc[m][n], 0, 0, 0);\
  __builtin_amdgcn_s_setprio(0); }

#define BARN(N) {                                                            \
  asm volatile("s_waitcnt vmcnt(" #N ") lgkmcnt(0)" ::: "memory");           \
  __builtin_amdgcn_s_barrier(); }

#define PH(cbuf, dbuf, ktd) {                                                \
  DMAT(dbuf, ktd); COMPUTE(cbuf);                                            \
  if constexpr (MODE != 2) { BARN(8); } }

template <int MODE>
__global__ __launch_bounds__(256, 2) void k_main(
    const _Float16* __restrict__ Af,    // [64000][1024] f16
    const _Float16* __restrict__ Wt,    // [512][1024] f16
    const float* __restrict__ Wc2s,     // [10][512]
    const float* __restrict__ wscore,   // [512]
    float* __restrict__ ws,
    float* __restrict__ dummy) {        // = d_out; garbage sink for MODE 1/2
  __shared__ _Float16 Ab[4][4096];   // 32 KB
  __shared__ _Float16 Wb[4][4096];   // 32 KB
  const int tid = threadIdx.x;
  const int lane = tid & 63;
  const int wv = tid >> 6;
  const int wm = wv >> 1, wn = wv & 1;

  const int l = blockIdx.x;
  const int lp = (l & 7) * 250 + (l >> 3);
  const int row0 = (lp >> 2) * BM;
  const int c0 = (lp & 3) * BN;

  const int lsub = (lane & 15), ksl = (lane >> 4) * 8;
  const _Float16* aA0 = Af + (size_t)(row0 + 2 * wv * 16 + lsub) * ENC2n + ksl;
  const _Float16* aA1 = aA0 + (size_t)16 * ENC2n;
  const _Float16* aW0 = Wt + (size_t)(c0 + 2 * wv * 16 + lsub) * ENC2n + ksl;
  const _Float16* aW1 = aW0 + (size_t)16 * ENC2n;

  f32x4 acc[4][4];
#pragma unroll
  for (int m = 0; m < 4; ++m)
#pragma unroll
    for (int n = 0; n < 4; ++n) acc[m][n] = (f32x4)0.f;

  const int reps = (MODE == 0) ? 1 : 4;
  for (int rep = 0; rep < reps; ++rep) {
    // prologue: tiles 0,1,2 in flight; force tile 0
    DMAT(0, 0);
    DMAT(1, 1);
    DMAT(2, 2);
    if constexpr (MODE != 2) { BARN(8); }

    for (int it = 0; it < 7; ++it) {
      const int p = it * 4;
      PH(0, 3, p + 3);
      PH(1, 0, p + 4);
      PH(2, 1, p + 5);
      PH(3, 2, p + 6);
    }
    PH(0, 3, 31);                                   // p=28, DMA tile 31
    COMPUTE(1); if constexpr (MODE != 2) { BARN(4); }
    COMPUTE(2); if constexpr (MODE != 2) { BARN(0); }
    COMPUTE(3);                                     // p=31
    if constexpr (MODE != 2) { __syncthreads(); }
  }

  if constexpr (MODE != 0) {
    // keep-alive dummy epilogue: garbage into d_out (softmax overwrites all)
    float s = 0.f;
#pragma unroll
    for (int m = 0; m < 4; ++m)
#pragma unroll
      for (int n = 0; n < 4; ++n)
        s += acc[m][n][0] + acc[m][n][1] + acc[m][n][2] + acc[m][n][3];
    dummy[(row0 + tid) % Mrows] = s;
    return;
  }

  // ---- real epilogue (MODE 0) ----
  __syncthreads();
  float* tcs = (float*)&Ab[0][0];
  {
    const float* __restrict__ tsrc = ws + (size_t)row0 * NKn;
    for (int i = tid; i < BM * NKn; i += 256) tcs[i] = tsrc[i];
  }
  __syncthreads();

  const float* __restrict__ DB = ws + OFF_DB;
  const int lr = lane & 15, lg = lane >> 4;
  float wc2[4][NKn], wsc[4];
  int cl[4];
#pragma unroll
  for (int fn = 0; fn < 4; ++fn) {
    cl[fn] = c0 + wn * 64 + fn * 16 + lr;
    wsc[fn] = wscore[cl[fn]];
#pragma unroll
    for (int k = 0; k < NKn; ++k) wc2[fn][k] = Wc2s[k * ATTNn + cl[fn]];
  }

#pragma unroll
  for (int fm = 0; fm < 4; ++fm) {
#pragma unroll
    for (int r = 0; r < 4; ++r) {
      const int rowL = wm * 64 + fm * 16 + lg * 4 + r;
      const int grow = row0 + rowL;
      const int b = grow / Tn;
      const float* __restrict__ tk = &tcs[rowL * NKn];
      float tkv[NKn];
#pragma unroll
      for (int k = 0; k < NKn; ++k) tkv[k] = tk[k];
      float p = 0.f;
#pragma unroll
      for (int fn = 0; fn < 4; ++fn) {
        float v = acc[fm][fn][r] + DB[b * ATTNn + cl[fn]];
#pragma unroll
        for (int k = 0; k < NKn; ++k) v = fmaf(tkv[k], wc2[fn][k], v);
        p = fmaf(wsc[fn], fast_tanh(v), p);
      }
      p += __shfl_down(p, 8, 16);
      p += __shfl_down(p, 4, 16);
      p += __shfl_down(p, 2, 16);
      p += __shfl_down(p, 1, 16);
      if (lr == 0) atomicAdd(&ws[OFF_SCORE + grow], p);
    }
  }
}

// ---------------------------------------------------------------------------
__global__ __launch_bounds__(256) void k_softmax(const float* __restrict__ ws,
                                                 const float* __restrict__ mask,
                                                 float* __restrict__ out) {
  const int b = blockIdx.x, tid = threadIdx.x;
  const float* __restrict__ s = ws + OFF_SCORE + b * Tn;
  const float* __restrict__ mrow = mask + b * Tn;
  float* __restrict__ orow = out + b * Tn;
  __shared__ float red[4];

  float m = -1e30f;
  for (int t = tid; t < Tn; t += 256) m = fmaxf(m, s[t]);
#pragma unroll
  for (int off = 32; off; off >>= 1) m = fmaxf(m, __shfl_down(m, off));
  if ((tid & 63) == 0) red[tid >> 6] = m;
  __syncthreads();
  m = fmaxf(fmaxf(red[0], red[1]), fmaxf(red[2], red[3]));
  __syncthreads();

  float sum = 0.f;
  for (int t = tid; t < Tn; t += 256) {
    const float e = expf(s[t] - m) * mrow[t];
    orow[t] = e;
    sum += e;
  }
#pragma unroll
  for (int off = 32; off; off >>= 1) sum += __shfl_down(sum, off);
  if ((tid & 63) == 0) red[tid >> 6] = sum;
  __syncthreads();
  sum = red[0] + red[1] + red[2] + red[3];
  const float inv = 1.f / sum;
  for (int t = tid; t < Tn; t += 256) orow[t] *= inv;
}

// ---------------------------------------------------------------------------
extern "C" void kernel_launch(void* const* d_in, const int* in_sizes, int n_in,
                              void* d_out, int out_size, void* d_ws, size_t ws_size,
                              hipStream_t stream) {
  const float* enc   = (const float*)d_in[0];
  const float* hid   = (const float*)d_in[1];
  const float* alpha = (const float*)d_in[2];
  const float* mask  = (const float*)d_in[3];
  const float* Wconv = (const float*)d_in[4];
  const float* Wc2s  = (const float*)d_in[5];
  const float* Wenc  = (const float*)d_in[6];
  const float* benc  = (const float*)d_in[7];
  const float* Wdec  = (const float*)d_in[8];
  const float* wscr  = (const float*)d_in[9];
  float* out = (float*)d_out;
  float* ws  = (float*)d_ws;
  _Float16* Wt = (_Float16*)(ws + OFF_WT);
  _Float16* Af = (_Float16*)(ws + OFF_AF16);

  k_wt<<<dim3(ENC2n / 32, ATTNn / 32), 256, 0, stream>>>(Wenc, Wt);
  k_conv<<<dim3((Tn + 255) / 256, Bn), 256, 0, stream>>>(alpha, Wconv, ws);
  k_dec<<<Bn, DECn, 0, stream>>>(hid, Wdec, benc, ws);
  k_acvt<<<4096, 256, 0, stream>>>(enc, Af);
  // ablation A/B (garbage into d_out; fully overwritten by k_softmax)
  k_main<1><<<2000, 256, 0, stream>>>(Af, Wt, Wc2s, wscr, ws, out);
  k_main<2><<<2000, 256, 0, stream>>>(Af, Wt, Wc2s, wscr, ws, out);
  // real
  k_main<0><<<2000, 256, 0, stream>>>(Af, Wt, Wc2s, wscr, ws, out);
  k_softmax<<<Bn, 256, 0, stream>>>(ws, mask, out);
}

// Round 13
// 258.531 us; speedup vs baseline: 4.7590x; 4.7590x over previous
//
#include <hip/hip_runtime.h>
#include <math.h>

// Problem constants
#define Bn    32
#define Tn    2000
#define Mrows (Bn * Tn)        // 64000
#define ENC2n 1024
#define ATTNn 512
#define DECn  512
#define NKn   10
#define KWn   100
#define PADn  50

// workspace layout (floats):
//   [0, 640000)            tmpconv [64000][10]
//   [OFF_DB, +16384)       DB[32][512] = b_enc + dec_e
//   [OFF_SCORE, +64000)    score [64000]
//   [OFF_WT, +262144)      Wt f16 [512 col][1024 k]
//   [OFF_AF16, ...)        Af16 [64000][1024] f16
#define OFF_DB    (Mrows * NKn)
#define OFF_SCORE (OFF_DB + Bn * ATTNn)
#define OFF_WT    (OFF_SCORE + Mrows)
#define OFF_AF16  (OFF_WT + 262144)

typedef _Float16 v8h __attribute__((ext_vector_type(8)));
typedef float f32x4 __attribute__((ext_vector_type(4)));

__device__ __forceinline__ float fast_tanh(float v) {
  const float e = __expf(2.f * v);
  return 1.f - 2.f * __builtin_amdgcn_rcpf(e + 1.f);
}

__device__ __forceinline__ void gload_lds16(const void* g, void* l) {
  __builtin_amdgcn_global_load_lds(
      (const __attribute__((address_space(1))) void*)g,
      (__attribute__((address_space(3))) void*)l, 16, 0, 0);
}

// ---------------------------------------------------------------------------
__global__ __launch_bounds__(256) void k_wt(const float* __restrict__ W,
                                            _Float16* __restrict__ Wt) {
  __shared__ float sh[32][33];
  const int x = threadIdx.x & 31, y = threadIdx.x >> 5;
  const int k0 = blockIdx.x * 32, c0 = blockIdx.y * 32;
  for (int i = y; i < 32; i += 8) sh[i][x] = W[(size_t)(k0 + i) * ATTNn + c0 + x];
  __syncthreads();
  for (int i = y; i < 32; i += 8)
    Wt[(size_t)(c0 + i) * ENC2n + k0 + x] = (_Float16)sh[x][i];
}

__global__ __launch_bounds__(256) void k_acvt(const float* __restrict__ A,
                                              _Float16* __restrict__ Af) {
  const size_t total = (size_t)Mrows * ENC2n;
  const size_t stride = (size_t)gridDim.x * 256 * 8;
  for (size_t i = ((size_t)blockIdx.x * 256 + threadIdx.x) * 8; i < total;
       i += stride) {
    const float4 a = *(const float4*)(A + i);
    const float4 b = *(const float4*)(A + i + 4);
    v8h h;
    h[0] = (_Float16)a.x; h[1] = (_Float16)a.y;
    h[2] = (_Float16)a.z; h[3] = (_Float16)a.w;
    h[4] = (_Float16)b.x; h[5] = (_Float16)b.y;
    h[6] = (_Float16)b.z; h[7] = (_Float16)b.w;
    *(v8h*)(Af + i) = h;
  }
}

__global__ __launch_bounds__(256) void k_conv(const float* __restrict__ alpha,
                                              const float* __restrict__ Wconv,
                                              float* __restrict__ ws) {
  __shared__ float sh[256 + KWn - 1];
  __shared__ float wc[NKn * KWn];
  const int b = blockIdx.y;
  const int t0 = blockIdx.x * 256;
  const int tid = threadIdx.x;

  for (int i = tid; i < NKn * KWn; i += 256) wc[i] = Wconv[i];
  const float* __restrict__ arow = alpha + b * Tn;
  for (int i = tid; i < 256 + KWn - 1; i += 256) {
    const int t = t0 - PADn + i;
    sh[i] = (t >= 0 && t < Tn) ? arow[t] : 0.f;
  }
  __syncthreads();

  const int t = t0 + tid;
  if (t < Tn) {
    float acc[NKn];
#pragma unroll
    for (int k = 0; k < NKn; ++k) acc[k] = 0.f;
    for (int i = 0; i < KWn; ++i) {
      const float a = sh[tid + i];
#pragma unroll
      for (int k = 0; k < NKn; ++k) acc[k] = fmaf(a, wc[k * KWn + i], acc[k]);
    }
    float* tp = ws + (size_t)(b * Tn + t) * NKn;
#pragma unroll
    for (int k = 0; k < NKn; ++k) tp[k] = acc[k];
    ws[OFF_SCORE + b * Tn + t] = 0.f;
  }
}

__global__ __launch_bounds__(512) void k_dec(const float* __restrict__ h,
                                             const float* __restrict__ Wdec,
                                             const float* __restrict__ benc,
                                             float* __restrict__ ws) {
  __shared__ float sh[DECn];
  const int b = blockIdx.x;
  const int a = threadIdx.x;
  sh[a] = h[b * DECn + a];
  __syncthreads();
  float acc = 0.f;
  for (int d = 0; d < DECn; ++d) acc = fmaf(sh[d], Wdec[d * ATTNn + a], acc);
  ws[OFF_DB + b * ATTNn + a] = benc[a] + acc;
}

#define BM 128
#define BK 32
#define NT (ENC2n / BK)   // 32

// ---------------------------------------------------------------------------
// k_main: BM=128 x BN=512 (full width), 512 threads / 8 waves; wave tile
// 64x128 (wr = wv>>2 row-half, wc = wv&3 col-quarter): 32 MFMA per phase
// from 12 ds_read_b128. Both operands DMA'd (global_load_lds, per-lane
// source -> fragment-major linear LDS, R9-proven zero conflicts). Depth-3:
// Ab[3] 8KB + Wb[3] 32KB = 120 KB. Per wave per phase: 1 A-DMA + 4 W-DMA;
// steady barrier = vmcnt(5) (forces exactly tile t+1's 5 loads; ~1-phase
// cover > HBM latency). No atomics: score reduced across the 4 col-waves
// in LDS, direct store.
// ---------------------------------------------------------------------------
#define DMAT(buf, kt) {                                                      \
  gload_lds16(aA + (size_t)(kt) * BK, &Ab[buf][wv * 512]);                   \
  gload_lds16(aW0 + (size_t)(kt) * BK, &Wb[buf][(wv * 4 + 0) * 512]);        \
  gload_lds16(aW1 + (size_t)(kt) * BK, &Wb[buf][(wv * 4 + 1) * 512]);        \
  gload_lds16(aW2 + (size_t)(kt) * BK, &Wb[buf][(wv * 4 + 2) * 512]);        \
  gload_lds16(aW3 + (size_t)(kt) * BK, &Wb[buf][(wv * 4 + 3) * 512]); }

#define COMPUTE(buf) {                                                       \
  v8h af[4], bf[8];                                                          \
  _Pragma("unroll")                                                          \
  for (int m = 0; m < 4; ++m)                                                \
    af[m] = *(const v8h*)&Ab[buf][(wr * 4 + m) * 512 + lane * 8];            \
  _Pragma("unroll")                                                          \
  for (int n = 0; n < 8; ++n)                                                \
    bf[n] = *(const v8h*)&Wb[buf][(wc * 8 + n) * 512 + lane * 8];            \
  __builtin_amdgcn_s_setprio(1);                                             \
  _Pragma("unroll")                                                          \
  for (int m = 0; m < 4; ++m)                                                \
    _Pragma("unroll")                                                        \
    for (int n = 0; n < 8; ++n)                                              \
      acc[m][n] = __builtin_amdgcn_mfma_f32_16x16x32_f16(af[m], bf[n],       \
                                                         acc[m][n], 0, 0, 0);\
  __builtin_amdgcn_s_setprio(0); }

#define BARN(N) {                                                            \
  asm volatile("s_waitcnt vmcnt(" #N ") lgkmcnt(0)" ::: "memory");           \
  __builtin_amdgcn_s_barrier(); }

#define PH(cbuf, dbuf, ktd) { DMAT(dbuf, ktd); COMPUTE(cbuf); BARN(5); }

__global__ __launch_bounds__(512, 2) void k_main(
    const _Float16* __restrict__ Af,    // [64000][1024] f16
    const _Float16* __restrict__ Wt,    // [512][1024] f16
    const float* __restrict__ Wc2s,     // [10][512]
    const float* __restrict__ wscore,   // [512]
    float* __restrict__ ws) {
  __shared__ _Float16 Ab[3][4096];     // 24 KB  (128 rows x 32 k)
  __shared__ _Float16 Wb[3][16384];    // 96 KB  (512 cols x 32 k)
  const int tid = threadIdx.x;
  const int lane = tid & 63;
  const int wv = tid >> 6;             // 0..7
  const int wr = wv >> 2, wc = wv & 3;

  const int row0 = blockIdx.x * BM;    // 500 blocks; W shared by all -> no swizzle

  // per-lane DMA sources: chunk c covers rows/cols c*16 + (lane&15),
  // k-slice (lane>>4)*8 f16. A: chunk wv. W: chunks wv*4 + 0..3.
  const int lsub = lane & 15, ksl = (lane >> 4) * 8;
  const _Float16* aA = Af + (size_t)(row0 + wv * 16 + lsub) * ENC2n + ksl;
  const _Float16* aW0 = Wt + (size_t)((wv * 4 + 0) * 16 + lsub) * ENC2n + ksl;
  const _Float16* aW1 = Wt + (size_t)((wv * 4 + 1) * 16 + lsub) * ENC2n + ksl;
  const _Float16* aW2 = Wt + (size_t)((wv * 4 + 2) * 16 + lsub) * ENC2n + ksl;
  const _Float16* aW3 = Wt + (size_t)((wv * 4 + 3) * 16 + lsub) * ENC2n + ksl;

  f32x4 acc[4][8];
#pragma unroll
  for (int m = 0; m < 4; ++m)
#pragma unroll
    for (int n = 0; n < 8; ++n) acc[m][n] = (f32x4)0.f;

  // ---- prologue: tiles 0,1 in flight; force tile 0 ----
  DMAT(0, 0);
  DMAT(1, 1);
  BARN(5);

  // ---- steady: p = 0..29, compute p from buf p%3, DMA p+2 -> buf (p+2)%3
  for (int it = 0; it < 10; ++it) {
    const int k2 = it * 3 + 2;
    PH(0, 2, k2 + 0);
    PH(1, 0, k2 + 1);
    PH(2, 1, k2 + 2);
  }
  // tail: p=30 (buf 0), force tile 31; p=31 (buf 1)
  COMPUTE(0);
  BARN(0);
  COMPUTE(1);

  // ---- epilogue (no atomics) ----
  __syncthreads();
  float* tcs = (float*)&Ab[0][0];        // [128][10] tmpconv slice (5 KB)
  float* sred = (float*)&Wb[0][0];       // [128][4] cross-wave partials (2 KB)
  {
    const float* __restrict__ tsrc = ws + (size_t)row0 * NKn;
    for (int i = tid; i < BM * NKn; i += 512) tcs[i] = tsrc[i];
  }
  __syncthreads();

  const float* __restrict__ DB = ws + OFF_DB;
  const int lr = lane & 15, lg = lane >> 4;
  float wc2[8][NKn], wsc[8];
  int cl[8];
#pragma unroll
  for (int fn = 0; fn < 8; ++fn) {
    cl[fn] = wc * 128 + fn * 16 + lr;
    wsc[fn] = wscore[cl[fn]];
#pragma unroll
    for (int k = 0; k < NKn; ++k) wc2[fn][k] = Wc2s[k * ATTNn + cl[fn]];
  }

#pragma unroll
  for (int fm = 0; fm < 4; ++fm) {
#pragma unroll
    for (int r = 0; r < 4; ++r) {
      const int rowL = wr * 64 + fm * 16 + lg * 4 + r;
      const int grow = row0 + rowL;
      const int b = grow / Tn;
      const float* __restrict__ tk = &tcs[rowL * NKn];
      float tkv[NKn];
#pragma unroll
      for (int k = 0; k < NKn; ++k) tkv[k] = tk[k];
      float p = 0.f;
#pragma unroll
      for (int fn = 0; fn < 8; ++fn) {
        float v = acc[fm][fn][r] + DB[b * ATTNn + cl[fn]];
#pragma unroll
        for (int k = 0; k < NKn; ++k) v = fmaf(tkv[k], wc2[fn][k], v);
        p = fmaf(wsc[fn], fast_tanh(v), p);
      }
      p += __shfl_down(p, 8, 16);
      p += __shfl_down(p, 4, 16);
      p += __shfl_down(p, 2, 16);
      p += __shfl_down(p, 1, 16);
      if (lr == 0) sred[rowL * 4 + wc] = p;
    }
  }
  __syncthreads();
  if (tid < BM) {
    ws[OFF_SCORE + row0 + tid] = sred[tid * 4 + 0] + sred[tid * 4 + 1] +
                                 sred[tid * 4 + 2] + sred[tid * 4 + 3];
  }
}

// ---------------------------------------------------------------------------
__global__ __launch_bounds__(256) void k_softmax(const float* __restrict__ ws,
                                                 const float* __restrict__ mask,
                                                 float* __restrict__ out) {
  const int b = blockIdx.x, tid = threadIdx.x;
  const float* __restrict__ s = ws + OFF_SCORE + b * Tn;
  const float* __restrict__ mrow = mask + b * Tn;
  float* __restrict__ orow = out + b * Tn;
  __shared__ float red[4];

  float m = -1e30f;
  for (int t = tid; t < Tn; t += 256) m = fmaxf(m, s[t]);
#pragma unroll
  for (int off = 32; off; off >>= 1) m = fmaxf(m, __shfl_down(m, off));
  if ((tid & 63) == 0) red[tid >> 6] = m;
  __syncthreads();
  m = fmaxf(fmaxf(red[0], red[1]), fmaxf(red[2], red[3]));
  __syncthreads();

  float sum = 0.f;
  for (int t = tid; t < Tn; t += 256) {
    const float e = expf(s[t] - m) * mrow[t];
    orow[t] = e;
    sum += e;
  }
#pragma unroll
  for (int off = 32; off; off >>= 1) sum += __shfl_down(sum, off);
  if ((tid & 63) == 0) red[tid >> 6] = sum;
  __syncthreads();
  sum = red[0] + red[1] + red[2] + red[3];
  const float inv = 1.f / sum;
  for (int t = tid; t < Tn; t += 256) orow[t] *= inv;
}

// ---------------------------------------------------------------------------
extern "C" void kernel_launch(void* const* d_in, const int* in_sizes, int n_in,
                              void* d_out, int out_size, void* d_ws, size_t ws_size,
                              hipStream_t stream) {
  const float* enc   = (const float*)d_in[0];
  const float* hid   = (const float*)d_in[1];
  const float* alpha = (const float*)d_in[2];
  const float* mask  = (const float*)d_in[3];
  const float* Wconv = (const float*)d_in[4];
  const float* Wc2s  = (const float*)d_in[5];
  const float* Wenc  = (const float*)d_in[6];
  const float* benc  = (const float*)d_in[7];
  const float* Wdec  = (const float*)d_in[8];
  const float* wscr  = (const float*)d_in[9];
  float* out = (float*)d_out;
  float* ws  = (float*)d_ws;
  _Float16* Wt = (_Float16*)(ws + OFF_WT);
  _Float16* Af = (_Float16*)(ws + OFF_AF16);

  k_wt<<<dim3(ENC2n / 32, ATTNn / 32), 256, 0, stream>>>(Wenc, Wt);
  k_conv<<<dim3((Tn + 255) / 256, Bn), 256, 0, stream>>>(alpha, Wconv, ws);
  k_dec<<<Bn, DECn, 0, stream>>>(hid, Wdec, benc, ws);
  k_acvt<<<4096, 256, 0, stream>>>(enc, Af);
  k_main<<<Mrows / BM, 512, 0, stream>>>(Af, Wt, Wc2s, wscr, ws);
  k_softmax<<<Bn, 256, 0, stream>>>(ws, mask, out);
}